// Round 12
// baseline (109.060 us; speedup 1.0000x reference)
//
#include <hip/hip_runtime.h>

// x: [8, 32, 32, 32, 32] fp32.  Flat = b*2^20 + i*32768 + j*1024 + k*32 + c
// W: [32, 256] row-major (o, 8 sections). Sections:
//   0:x 1:mean_i 2:mean_j 3:mean_k 4:mean_ij 5:mean_ik 6:mean_jk 7:mean_ijk
// out[b,i,j,k,o] = W0.x + B1[b,j,k,o] + B2[b,i,k,o] + A3[b,i,j,o]
//                + A12[b,k,o] + A13[b,j,o] + A23[b,i,o] + A123[b,o] + bias[o]
// R18: isolate R1's fold. reduce blocks own complete S-rows at the end ->
// project B1/B2/A3 in-block (128 FMA/thread, free under BW-bound stream);
// S3 stays in LDS only (global S3 round-trip deleted, -16MB). mid shrinks
// to pools-only (24 blocks). Unlike R1 (which bundled seg-interleave +
// register-dbuf + final rewrite and regressed +24 unattributed), block
// mapping here is R4-verbatim (0-255 seg0, 256-511 segA) and final is R17
// (equal-best 107.7). Ledger: 8 nulls at 107-114; ideal ~71us.

static __device__ __forceinline__ float4 f4add(float4 a, float4 b) {
  a.x += b.x; a.y += b.y; a.z += b.z; a.w += b.w; return a;
}

// grid 512. LDS (union): segA = sT 8224 | sS3 1056 | wt2 1024 | wt3 1024
// = 11328 floats (45.3KB, 3 blocks/CU cap; grid needs 2/CU). seg0 uses
// wt1 = smem (1024), sS = smem+1024 ([32][36] = 1152).
__global__ __launch_bounds__(256) void reduce_proj_kernel(
    const float* __restrict__ x, const float* __restrict__ W,
    float* __restrict__ S1, float* __restrict__ S2,
    float* __restrict__ B1, float* __restrict__ B2,
    float* __restrict__ A3o) {
  __shared__ float smem[11328];
  const int t = threadIdx.x;

  if (blockIdx.x < 256) {
    // seg0: S1[b, j=a, k, c] = sum_i x[b,i,a,k,c]; then B1 row = S1row·W1^T/32
    float* wt1 = smem;             // W sec1 transposed [c*32+o]
    float* sS  = smem + 1024;      // [32][36] padded row stage
    const int b = blockIdx.x >> 5, a = blockIdx.x & 31;
    #pragma unroll
    for (int m = 0; m < 4; ++m) {
      const int e = t + 256 * m;
      wt1[e] = W[(e & 31) * 256 + 1 * 32 + (e >> 5)];
    }
    const float* base = x + ((size_t)b << 20) + a * 1024 + 4 * t;
    float4 acc = make_float4(0.f, 0.f, 0.f, 0.f);
    #pragma unroll
    for (int i = 0; i < 32; ++i) acc = f4add(acc, *(const float4*)(base + i * 32768));
    ((float4*)(S1 + (size_t)(b * 32 + a) * 1024))[t] = acc;   // pool needs S1
    // stage row quad (k = t>>3, c0 = 4*(t&7)) into padded [32][36]
    *(float4*)(sS + (t >> 3) * 36 + 4 * (t & 7)) = acc;
    __syncthreads();
    // project: thread (kk = t>>3, og = t&7); float4 idx kk*8+og == t
    const int kk = t >> 3, og = t & 7;
    const float4* wt4 = (const float4*)wt1;
    float4 o1 = make_float4(0.f, 0.f, 0.f, 0.f);
    #pragma unroll
    for (int c = 0; c < 32; ++c) {
      const float xv = sS[kk * 36 + c];
      const float4 w = wt4[c * 8 + og];
      o1.x += xv * w.x; o1.y += xv * w.y; o1.z += xv * w.z; o1.w += xv * w.w;
    }
    const float s = 1.f / 32.f;
    o1.x *= s; o1.y *= s; o1.z *= s; o1.w *= s;
    ((float4*)(B1 + (size_t)(b * 32 + a) * 1024))[t] = o1;
  } else {
    // segA: block (b, i=a): stream slab once -> S2 row (global+proj B2),
    // S3 row (LDS only -> proj A3). R4 loop structure verbatim.
    float* sT  = smem;             // [8][1028] tile
    float* sS3 = smem + 8224;      // [32][33] sum_k rows
    float* wt2 = smem + 9280;      // W sec2 transposed
    float* wt3 = smem + 10304;     // W sec3 transposed
    const int idx = blockIdx.x - 256;
    const int b = idx >> 5, a = idx & 31;
    #pragma unroll
    for (int m = 0; m < 4; ++m) {
      const int e = t + 256 * m;
      wt2[e] = W[(e & 31) * 256 + 2 * 32 + (e >> 5)];
      wt3[e] = W[(e & 31) * 256 + 3 * 32 + (e >> 5)];
    }
    const float* slab = x + ((size_t)b << 20) + a * 32768;
    float4 accS2 = make_float4(0.f, 0.f, 0.f, 0.f);
    const int jl = t >> 5, cc = t & 31;      // S3 role: (j_loc, c)

    for (int jt = 0; jt < 4; ++jt) {
      const float4* src4 = (const float4*)(slab + jt * 8192);
      #pragma unroll
      for (int m = 0; m < 8; ++m) {
        const int q = t + 256 * m;           // float4 idx in tile
        const float4 v = src4[q];
        float* p = sT + (q >> 8) * 1028 + 4 * (q & 255);
        p[0] = v.x; p[1] = v.y; p[2] = v.z; p[3] = v.w;
      }
      __syncthreads();
      #pragma unroll
      for (int j = 0; j < 8; ++j)
        accS2 = f4add(accS2, *(const float4*)(sT + j * 1028 + 4 * t));
      float s3 = 0.f;
      #pragma unroll
      for (int k = 0; k < 32; ++k) s3 += sT[jl * 1028 + k * 32 + cc];
      sS3[(jt * 8 + jl) * 33 + cc] = s3;     // banks (j+c)%32: 2-way, free
      __syncthreads();
    }
    ((float4*)(S2 + (size_t)(b * 32 + a) * 1024))[t] = accS2;  // pool needs S2
    *(float4*)(sT + (t >> 3) * 36 + 4 * (t & 7)) = accS2;      // reuse sT
    __syncthreads();
    const int kk = t >> 3, og = t & 7;
    const float4* w24 = (const float4*)wt2;
    const float4* w34 = (const float4*)wt3;
    float4 o2 = make_float4(0.f, 0.f, 0.f, 0.f);
    float4 o3 = make_float4(0.f, 0.f, 0.f, 0.f);
    #pragma unroll
    for (int c = 0; c < 32; ++c) {
      const float x2 = sT[kk * 36 + c];
      const float4 w2 = w24[c * 8 + og];
      o2.x += x2 * w2.x; o2.y += x2 * w2.y; o2.z += x2 * w2.z; o2.w += x2 * w2.w;
      const float x3 = sS3[kk * 33 + c];     // kk = j here; banks (j+c)%32 ok
      const float4 w3 = w34[c * 8 + og];
      o3.x += x3 * w3.x; o3.y += x3 * w3.y; o3.z += x3 * w3.z; o3.w += x3 * w3.w;
    }
    const float s = 1.f / 32.f;
    o2.x *= s; o2.y *= s; o2.z *= s; o2.w *= s;
    o3.x *= s; o3.y *= s; o3.z *= s; o3.w *= s;
    ((float4*)(B2  + (size_t)(b * 32 + a) * 1024))[t] = o2;
    ((float4*)(A3o + (size_t)(b * 32 + a) * 1024))[t] = o3;
  }
}

// pools only: 24 blocks (seg*8 + b). Block 0 also publishes W0t.
__global__ __launch_bounds__(256) void pool_kernel(
    const float* __restrict__ S1, const float* __restrict__ S2,
    const float* __restrict__ W,
    float* __restrict__ A12g, float* __restrict__ A13g,
    float* __restrict__ A23g, float* __restrict__ A123g,
    float* __restrict__ W0t) {
  __shared__ float smem[3104];
  const int t = threadIdx.x;
  const int seg = blockIdx.x >> 3, b = blockIdx.x & 7;
  float* sBuf  = smem;          // [32][32] second-level sums
  float* sW    = smem + 1024;   // section 4+seg transposed [c*32+o]
  float* sW7   = smem + 2048;   // section 7 transposed
  float* sS123 = smem + 3072;   // [32]
  const int sec = 4 + seg;

  #pragma unroll
  for (int m = 0; m < 4; ++m) {
    const int e = t + 256 * m, c = e >> 5, o = e & 31;
    sW[e] = W[o * 256 + sec * 32 + c];
    if (seg == 0) sW7[e] = W[o * 256 + 7 * 32 + c];
  }
  if (blockIdx.x == 0) {
    #pragma unroll
    for (int m = 0; m < 4; ++m) {
      const int e = t + 256 * m;
      W0t[e] = W[(e & 31) * 256 + (e >> 5)];   // W0t[c*32+o]
    }
  }
  const float* Sb = ((seg == 2) ? S2 : S1) + (size_t)b * 32768;
  #pragma unroll
  for (int m = 0; m < 4; ++m) {
    const int e = t + 256 * m, a = e >> 5, c = e & 31;
    float s = 0.f;
    if (seg == 0) {              // S12[k=a,c] = sum_j S1[b,j,a,c]
      for (int j = 0; j < 32; ++j) s += Sb[j * 1024 + a * 32 + c];
    } else {                     // S13/S23[(j|i)=a,c] = sum_k
      for (int k = 0; k < 32; ++k) s += Sb[a * 1024 + k * 32 + c];
    }
    sBuf[e] = s;
  }
  __syncthreads();
  if (seg == 0 && t < 32) {
    float s = 0.f;
    for (int k = 0; k < 32; ++k) s += sBuf[k * 32 + t];
    sS123[t] = s;
  }
  __syncthreads();
  float* Ag = (seg == 0) ? A12g : (seg == 1) ? A13g : A23g;
  #pragma unroll
  for (int m = 0; m < 4; ++m) {
    const int e = t + 256 * m, a = e >> 5, o = e & 31;
    float s = 0.f;
    #pragma unroll
    for (int c = 0; c < 32; ++c) s += sW[c * 32 + o] * sBuf[a * 32 + c];
    Ag[b * 1024 + e] = s * (1.f / 1024.f);
  }
  if (seg == 0 && t < 32) {
    float s = 0.f;
    #pragma unroll
    for (int c = 0; c < 32; ++c) s += sW7[c * 32 + t] * sS123[c];
    A123g[b * 32 + t] = s * (1.f / 32768.f);
  }
}

// 64 rows/block, 4096 blocks (R17 verbatim). LDS 12.5KB -> 8 blocks/CU.
// Thread = (rg=t>>3: 2 rows, og=t&7: 4 outs). Tables hoisted + precombined.
__global__ __launch_bounds__(256) void final_kernel(
    const float* __restrict__ x, const float* __restrict__ W0t,
    const float* __restrict__ B1, const float* __restrict__ B2,
    const float* __restrict__ A3o, const float* __restrict__ A12g,
    const float* __restrict__ A13g, const float* __restrict__ A23g,
    const float* __restrict__ A123g, const float* __restrict__ bias,
    float* __restrict__ out) {
  __shared__ float xs[64 * 33];
  __shared__ float wt[1024];     // W0 transposed [c*32+o]
  const int t = threadIdx.x;
  const size_t pos0 = (size_t)blockIdx.x * 64;

  const int rg = t >> 3, og = t & 7;
  const int lrow0 = 2 * rg;
  const size_t p0 = pos0 + lrow0;
  const int k0 = (int)(p0 & 31), j = (int)(p0 >> 5) & 31,
            i = (int)(p0 >> 10) & 31, b = (int)(p0 >> 15);
  const int oo = og * 4;

  const float4 va3  = *(const float4*)(A3o  + ((size_t)((b * 32 + i) * 32 + j)) * 32 + oo);
  const float4 va13 = *(const float4*)(A13g + (size_t)(b * 32 + j) * 32 + oo);
  const float4 va23 = *(const float4*)(A23g + (size_t)(b * 32 + i) * 32 + oo);
  const float4 va123= *(const float4*)(A123g + (size_t)b * 32 + oo);
  const float4 vbi  = *(const float4*)(bias + oo);
  float4 vb1[2], vb2[2], v12[2];
  #pragma unroll
  for (int r = 0; r < 2; ++r) {
    const int k = k0 + r;
    vb1[r] = *(const float4*)(B1 + ((size_t)((b * 32 + j) * 32 + k)) * 32 + oo);
    vb2[r] = *(const float4*)(B2 + ((size_t)((b * 32 + i) * 32 + k)) * 32 + oo);
    v12[r] = *(const float4*)(A12g + (size_t)(b * 32 + k) * 32 + oo);
  }

  const float4* xp4 = (const float4*)(x + pos0 * 32);
  #pragma unroll
  for (int m = 0; m < 2; ++m) {
    const int q = t + 256 * m;
    const float4 v = xp4[q];
    float* p = xs + (q >> 3) * 33 + 4 * (q & 7);
    p[0] = v.x; p[1] = v.y; p[2] = v.z; p[3] = v.w;
  }
  #pragma unroll
  for (int m = 0; m < 4; ++m) wt[t + 256 * m] = W0t[t + 256 * m];
  __syncthreads();

  float tb[2][4];
  #pragma unroll
  for (int r = 0; r < 2; ++r) {
    tb[r][0] = va3.x + va13.x + va23.x + va123.x + vbi.x + vb1[r].x + vb2[r].x + v12[r].x;
    tb[r][1] = va3.y + va13.y + va23.y + va123.y + vbi.y + vb1[r].y + vb2[r].y + v12[r].y;
    tb[r][2] = va3.z + va13.z + va23.z + va123.z + vbi.z + vb1[r].z + vb2[r].z + v12[r].z;
    tb[r][3] = va3.w + va13.w + va23.w + va123.w + vbi.w + vb1[r].w + vb2[r].w + v12[r].w;
  }

  float acc[2][4];
  #pragma unroll
  for (int r = 0; r < 2; ++r)
    #pragma unroll
    for (int u = 0; u < 4; ++u) acc[r][u] = 0.f;

  const float4* wt4 = (const float4*)wt;
  #pragma unroll
  for (int c = 0; c < 32; ++c) {
    const float4 w = wt4[c * 8 + og];
    #pragma unroll
    for (int r = 0; r < 2; ++r) {
      const float xv = xs[(lrow0 + r) * 33 + c];
      acc[r][0] += xv * w.x; acc[r][1] += xv * w.y;
      acc[r][2] += xv * w.z; acc[r][3] += xv * w.w;
    }
  }

  #pragma unroll
  for (int r = 0; r < 2; ++r) {
    *(float4*)(out + (p0 + r) * 32 + oo) = make_float4(
        acc[r][0] + tb[r][0], acc[r][1] + tb[r][1],
        acc[r][2] + tb[r][2], acc[r][3] + tb[r][3]);
  }
}

extern "C" void kernel_launch(void* const* d_in, const int* in_sizes, int n_in,
                              void* d_out, int out_size, void* d_ws, size_t ws_size,
                              hipStream_t stream) {
  const float* x    = (const float*)d_in[0];
  const float* W    = (const float*)d_in[1];
  const float* bias = (const float*)d_in[2];
  float* out = (float*)d_out;
  float* ws  = (float*)d_ws;
  float* S1    = ws;                // 262144
  float* S2    = ws + 262144;
  float* B1    = ws + 524288;
  float* B2    = ws + 786432;
  float* A3o   = ws + 1048576;
  float* W0t   = ws + 1310720;      // 1024
  float* A12g  = ws + 1311744;      // 8192
  float* A13g  = ws + 1319936;      // 8192
  float* A23g  = ws + 1328128;      // 8192
  float* A123g = ws + 1336320;      // 256

  reduce_proj_kernel<<<512, 256, 0, stream>>>(x, W, S1, S2, B1, B2, A3o);
  pool_kernel<<<24, 256, 0, stream>>>(S1, S2, W, A12g, A13g, A23g, A123g, W0t);
  final_kernel<<<4096, 256, 0, stream>>>(x, W0t, B1, B2, A3o, A12g, A13g,
                                         A23g, A123g, bias, out);
}